// Round 10
// baseline (36.355 us; speedup 1.0000x reference)
//
#include <hip/hip_runtime.h>
#include <hip/hip_bf16.h>

typedef __attribute__((ext_vector_type(8))) short bf16x8;
typedef __attribute__((ext_vector_type(4))) float f32x4;
typedef __attribute__((ext_vector_type(16))) float f32x16;

#define NB 8192
#define NS 8

__device__ __forceinline__ unsigned short f2bf(float f) {
  union { float f; unsigned int u; } v; v.f = f;
  unsigned int r = v.u + 0x7FFFu + ((v.u >> 16) & 1u);
  return (unsigned short)(r >> 16);
}

// prep: W2 -> bf16 B-fragments for 32x32x16 (w2f); Wc = [W_emb;b_emb]@W1a (wc);
//       W1b (rows 64..127) -> bf16 B-fragments for 16x16x32 (w1bf)
__global__ __launch_bounds__(256) void prep_kernel(
    const float* __restrict__ W2, const float* __restrict__ W_emb,
    const float* __restrict__ b_emb, const float* __restrict__ W1,
    unsigned short* __restrict__ w2f, float* __restrict__ wc,
    unsigned short* __restrict__ w1bf) {
  int tid = blockIdx.x * 256 + threadIdx.x;
  if (tid < 8192) {
    // 32x32x16 B-frag granules: granule = (nt*4 + s)*64 + lane
    int lane = tid & 63;
    int s = (tid >> 6) & 3;
    int nt = tid >> 8;                 // 0..31 (32-col tiles)
    int col = nt * 32 + (lane & 31);
    int kb = s * 16 + (lane >> 5) * 8;
    bf16x8 pk;
#pragma unroll
    for (int e = 0; e < 8; ++e)
      pk[e] = (short)f2bf(W2[(kb + e) * 1024 + col]);
    *(bf16x8*)(w2f + tid * 8) = pk;
  } else if (tid < 8192 + 192) {
    int t2 = tid - 8192;
    int c = t2 >> 6, k = t2 & 63;
    float s = 0.f;
    for (int e = 0; e < 64; ++e) {
      float src = (c < 2) ? W_emb[c * 64 + e] : b_emb[e];
      s += src * W1[e * 64 + k];
    }
    wc[t2] = s;  // wc0[k], wc1[k], cbe[k]
  } else if (tid < 8192 + 192 + 512) {
    int q = tid - 8384;
    int lane = q & 63;
    int fr = q >> 6;          // nt*2 + ks  (16x16x32 frag for hW)
    int nt = fr >> 1, ks = fr & 1;
    int col = nt * 16 + (lane & 15);
    int e0 = ks * 32 + (lane >> 4) * 8;
    bf16x8 pk;
#pragma unroll
    for (int e = 0; e < 8; ++e)
      pk[e] = (short)f2bf(W1[(64 + e0 + e) * 64 + col]);
    *(bf16x8*)(w1bf + q * 8) = pk;
  }
}

// pool: block = (group, col-half), 256 threads (4 waves), 4 blocks/CU.
// Phase 0: fused hW tile (16x16x32 MFMA) into LDS.
// Phase 1: A built into LDS as 8 j-pair tiles (32 rows x 64 k), rows 0-15 = j=p,
//          rows 16-31 = j=p+8, in 32x32x16 fragment order.
// Phase 2: per pass (2 ntiles of 32 cols): 8 pairs x 8 MFMA (32x32x16);
//          pool over j-pair = in-register fmax(acc[q], acc[q+8]); then over pairs.
__global__ __launch_bounds__(256, 4) void pool_kernel(
    const float* __restrict__ in_xy, const float* __restrict__ h_states,
    const float* __restrict__ b1, const float* __restrict__ b2,
    const unsigned short* __restrict__ w2f, const float* __restrict__ wc,
    const unsigned short* __restrict__ w1bf, float* __restrict__ out) {
  __shared__ bf16x8 Afrag[2048];  // 32 KB: granule (p*4+s)*64+lane
  __shared__ float hWs[16][72];   // hW tile (pad 72)
  __shared__ float exy[32];       // x[0:16], y[16:32]
  const int g = blockIdx.x >> 1;
  const int half = blockIdx.x & 1;
  const int t = threadIdx.x;
  const int lane = t & 63;
  const int wv = t >> 6;  // 0..3

  if (t < 32) {
    int p = t & 15;
    exy[t] = in_xy[((NS - 1) * NB + g * 16 + p) * 2 + (t >> 4)];
  }

  // Phase 0: hW[j][k] = b1[k] + cbe[k] + h[g*16+j] @ W1b. Wave wv -> ntile wv.
  {
    const int row = g * 16 + (lane & 15);
    const int e0 = (lane >> 4) * 8;
    const float* hp = h_states + row * 64 + e0;
    bf16x8 ha0, ha1;
#pragma unroll
    for (int e = 0; e < 8; ++e) {
      ha0[e] = (short)f2bf(hp[e]);
      ha1[e] = (short)f2bf(hp[e + 32]);
    }
    bf16x8 bf0 = *(const bf16x8*)(w1bf + ((wv * 2 + 0) * 64 + lane) * 8);
    bf16x8 bf1 = *(const bf16x8*)(w1bf + ((wv * 2 + 1) * 64 + lane) * 8);
    f32x4 z = {0.f, 0.f, 0.f, 0.f};
    f32x4 acc = __builtin_amdgcn_mfma_f32_16x16x32_bf16(ha0, bf0, z, 0, 0, 0);
    acc = __builtin_amdgcn_mfma_f32_16x16x32_bf16(ha1, bf1, acc, 0, 0, 0);
    int col = wv * 16 + (lane & 15);
    float bb = b1[col] + wc[128 + col];
#pragma unroll
    for (int r = 0; r < 4; ++r)
      hWs[(lane >> 4) * 4 + r][col] = acc[r] + bb;
  }

  // Per-thread A-build constants: row = t&31 -> i = t&15, jsel = (t>>4)&1;
  // k-chunk: k0 = s*16 + khalf*8, s=(t>>6)&3... for 256 threads: s=(t>>6)&3
  const int i = t & 15;
  const int jsel = (t >> 4) & 1;
  const int k0 = ((t >> 6) & 3) * 16 + ((t >> 5) & 1) * 8;
  float w0[8], w1[8];
#pragma unroll
  for (int e = 0; e < 8; ++e) {
    w0[e] = wc[k0 + e];
    w1[e] = wc[64 + k0 + e];
  }
  __syncthreads();

  // Phase 1: A build. Granule G = t + 256c -> pair p=c, within-pair index t:
  // lane=t&63 (row=t&31), k-chunk from bits 5..7. j = p + 8*jsel.
  {
    float exi = exy[i], eyi = exy[16 + i];
#pragma unroll
    for (int c = 0; c < 8; ++c) {
      int j = c + 8 * jsel;
      float rx = exy[j] - exi;
      float ry = exy[16 + j] - eyi;
      const f32x4* hp2 = (const f32x4*)&hWs[j][k0];
      f32x4 h0 = hp2[0], h1 = hp2[1];
      float hv[8] = {h0[0], h0[1], h0[2], h0[3], h1[0], h1[1], h1[2], h1[3]};
      bf16x8 pk;
#pragma unroll
      for (int e = 0; e < 8; ++e) {
        float v = fmaf(rx, w0[e], fmaf(ry, w1[e], hv[e]));
        v = fmaxf(v, 0.f);
        pk[e] = (short)f2bf(v);
      }
      Afrag[t + 256 * c] = pk;
    }
  }
  __syncthreads();

  // Phase 2: 32x32x16 GEMM + register pooling. Wave owns 128 cols; 2 passes x 2 ntiles.
  const int colloc = half * 512 + wv * 128;
#pragma unroll
  for (int pass = 0; pass < 2; ++pass) {
    bf16x8 bfr[2][4];
#pragma unroll
    for (int u = 0; u < 2; ++u) {
      int nt = (colloc >> 5) + pass * 2 + u;
#pragma unroll
      for (int s = 0; s < 4; ++s)
        bfr[u][s] = *(const bf16x8*)(w2f + (((nt * 4 + s) * 64 + lane) * 8));
    }
    float pool[2][8];
#pragma unroll
    for (int u = 0; u < 2; ++u)
#pragma unroll
      for (int q = 0; q < 8; ++q) pool[u][q] = -3.4e38f;

    bf16x8 af0 = Afrag[0 * 64 + lane];
    bf16x8 af1 = Afrag[1 * 64 + lane];
    bf16x8 af2 = Afrag[2 * 64 + lane];
    bf16x8 af3 = Afrag[3 * 64 + lane];
#pragma unroll
    for (int p = 0; p < 8; ++p) {
      f32x16 acc[2];
      __builtin_amdgcn_s_setprio(1);
#pragma unroll
      for (int u = 0; u < 2; ++u) {
        f32x16 z = {0.f};
        acc[u] = __builtin_amdgcn_mfma_f32_32x32x16_bf16(af0, bfr[u][0], z, 0, 0, 0);
      }
#pragma unroll
      for (int u = 0; u < 2; ++u)
        acc[u] = __builtin_amdgcn_mfma_f32_32x32x16_bf16(af1, bfr[u][1], acc[u], 0, 0, 0);
#pragma unroll
      for (int u = 0; u < 2; ++u)
        acc[u] = __builtin_amdgcn_mfma_f32_32x32x16_bf16(af2, bfr[u][2], acc[u], 0, 0, 0);
#pragma unroll
      for (int u = 0; u < 2; ++u)
        acc[u] = __builtin_amdgcn_mfma_f32_32x32x16_bf16(af3, bfr[u][3], acc[u], 0, 0, 0);
      __builtin_amdgcn_s_setprio(0);
      int pn = (p + 1) & 7;  // wrap harmless
      af0 = Afrag[(pn * 4 + 0) * 64 + lane];
      af1 = Afrag[(pn * 4 + 1) * 64 + lane];
      af2 = Afrag[(pn * 4 + 2) * 64 + lane];
      af3 = Afrag[(pn * 4 + 3) * 64 + lane];
      // pool over the j-pair (rows r and r+16 = regs q and q+8), then over pairs
#pragma unroll
      for (int u = 0; u < 2; ++u)
#pragma unroll
        for (int q = 0; q < 8; ++q)
          pool[u][q] = fmaxf(pool[u][q], fmaxf(acc[u][q], acc[u][q + 8]));
    }
    // Epilogue: bias + relu + store. i = (q&3) + 8*(q>>2) + 4*(lane>>5).
#pragma unroll
    for (int u = 0; u < 2; ++u) {
      int col = colloc + pass * 64 + u * 32 + (lane & 31);
      float bb = b2[col];
#pragma unroll
      for (int q = 0; q < 8; ++q) {
        int io = (q & 3) + 8 * (q >> 2) + 4 * (lane >> 5);
        out[(g * 16 + io) * 1024 + col] = fmaxf(pool[u][q] + bb, 0.f);
      }
    }
  }
}

extern "C" void kernel_launch(void* const* d_in, const int* in_sizes, int n_in,
                              void* d_out, int out_size, void* d_ws, size_t ws_size,
                              hipStream_t stream) {
  const float* in_xy = (const float*)d_in[0];
  const float* h_states = (const float*)d_in[2];
  const float* W_emb = (const float*)d_in[4];
  const float* b_emb = (const float*)d_in[5];
  const float* W1 = (const float*)d_in[6];
  const float* b1 = (const float*)d_in[7];
  const float* W2 = (const float*)d_in[8];
  const float* b2 = (const float*)d_in[9];
  float* out = (float*)d_out;

  unsigned short* w2f = (unsigned short*)d_ws;                     // 128 KB @ 0
  float* wc = (float*)((char*)d_ws + 131072);                      // 768 B
  unsigned short* w1bf = (unsigned short*)((char*)d_ws + 132096);  // 8 KB

  prep_kernel<<<35, 256, 0, stream>>>(W2, W_emb, b_emb, W1, w2f, wc, w1bf);
  pool_kernel<<<1024, 256, 0, stream>>>(in_xy, h_states, b1, b2, w2f, wc, w1bf, out);
}

// Round 11
// 29.881 us; speedup vs baseline: 1.2167x; 1.2167x over previous
//
#include <hip/hip_runtime.h>
#include <hip/hip_bf16.h>

typedef __attribute__((ext_vector_type(8))) short bf16x8;
typedef __attribute__((ext_vector_type(4))) float f32x4;

#define NB 8192
#define NS 8

__device__ __forceinline__ unsigned short f2bf(float f) {
  union { float f; unsigned int u; } v; v.f = f;
  unsigned int r = v.u + 0x7FFFu + ((v.u >> 16) & 1u);
  return (unsigned short)(r >> 16);
}

// prep: W2 -> bf16 B-fragments (w2f); Wc = [W_emb;b_emb]@W1a (wc);
//       W1b (rows 64..127) -> bf16 B-fragments (w1bf)
__global__ __launch_bounds__(256) void prep_kernel(
    const float* __restrict__ W2, const float* __restrict__ W_emb,
    const float* __restrict__ b_emb, const float* __restrict__ W1,
    unsigned short* __restrict__ w2f, float* __restrict__ wc,
    unsigned short* __restrict__ w1bf) {
  int tid = blockIdx.x * 256 + threadIdx.x;
  if (tid < 8192) {
    int lane = tid & 63;
    int ks = (tid >> 6) & 1;
    int nt = tid >> 7;
    int col = nt * 16 + (lane & 15);
    int k0 = ks * 32 + (lane >> 4) * 8;
    bf16x8 pk;
#pragma unroll
    for (int e = 0; e < 8; ++e)
      pk[e] = (short)f2bf(W2[(k0 + e) * 1024 + col]);
    *(bf16x8*)(w2f + tid * 8) = pk;
  } else if (tid < 8192 + 192) {
    int t2 = tid - 8192;
    int c = t2 >> 6, k = t2 & 63;
    float s = 0.f;
    for (int e = 0; e < 64; ++e) {
      float src = (c < 2) ? W_emb[c * 64 + e] : b_emb[e];
      s += src * W1[e * 64 + k];
    }
    wc[t2] = s;  // wc0[k], wc1[k], cbe[k]
  } else if (tid < 8192 + 192 + 512) {
    int q = tid - 8384;
    int lane = q & 63;
    int fr = q >> 6;          // nt*2 + ks
    int nt = fr >> 1, ks = fr & 1;
    int col = nt * 16 + (lane & 15);
    int e0 = ks * 32 + (lane >> 4) * 8;
    bf16x8 pk;
#pragma unroll
    for (int e = 0; e < 8; ++e)
      pk[e] = (short)f2bf(W1[(64 + e0 + e) * 64 + col]);
    *(bf16x8*)(w1bf + q * 8) = pk;
  }
}

// pool: block = (group, col-half), 256 threads (4 waves), 4 blocks/CU.
// Phase 0: fused hW tile (wave wv -> ntile wv, 2 MFMAs) into LDS.
// Phase 1: A (tile=j) built into LDS in fragment order; pass-0 B-fragments
//          issued BEFORE the barrier so global latency overlaps A-build.
// Phase 2: 256x512x64 MFMA GEMM, register max-pool over j. K split into two
//          independent accumulators (acc0 = a0.B0, acc1 = a1.B1) so all 8
//          MFMAs per iteration are independent; pool = fmax(pool, acc0+acc1).
__global__ __launch_bounds__(256, 4) void pool_kernel(
    const float* __restrict__ in_xy, const float* __restrict__ h_states,
    const float* __restrict__ b1, const float* __restrict__ b2,
    const unsigned short* __restrict__ w2f, const float* __restrict__ wc,
    const unsigned short* __restrict__ w1bf, float* __restrict__ out) {
  __shared__ bf16x8 Afrag[2048];  // 32 KB, fragment-ordered A (256x64 bf16), tile=j
  __shared__ float hWs[16][72];   // hW tile (pad 72 -> 16B-aligned rows)
  __shared__ float exy[32];       // x[0:16], y[16:32]
  const int g = blockIdx.x >> 1;
  const int half = blockIdx.x & 1;
  const int t = threadIdx.x;
  const int lane = t & 63;
  const int wv = t >> 6;  // 0..3

  if (t < 32) {
    int p = t & 15;
    exy[t] = in_xy[((NS - 1) * NB + g * 16 + p) * 2 + (t >> 4)];
  }

  // Phase 0: hW[j][k] = b1[k] + cbe[k] + h[g*16+j] @ W1b. Wave wv -> ntile wv.
  {
    const int row = g * 16 + (lane & 15);
    const int e0 = (lane >> 4) * 8;
    const float* hp = h_states + row * 64 + e0;
    bf16x8 ha0, ha1;
#pragma unroll
    for (int e = 0; e < 8; ++e) {
      ha0[e] = (short)f2bf(hp[e]);
      ha1[e] = (short)f2bf(hp[e + 32]);
    }
    bf16x8 bf0 = *(const bf16x8*)(w1bf + ((wv * 2 + 0) * 64 + lane) * 8);
    bf16x8 bf1 = *(const bf16x8*)(w1bf + ((wv * 2 + 1) * 64 + lane) * 8);
    f32x4 z = {0.f, 0.f, 0.f, 0.f};
    f32x4 acc = __builtin_amdgcn_mfma_f32_16x16x32_bf16(ha0, bf0, z, 0, 0, 0);
    acc = __builtin_amdgcn_mfma_f32_16x16x32_bf16(ha1, bf1, acc, 0, 0, 0);
    int col = wv * 16 + (lane & 15);
    float bb = b1[col] + wc[128 + col];
#pragma unroll
    for (int r = 0; r < 4; ++r)
      hWs[(lane >> 4) * 4 + r][col] = acc[r] + bb;
  }

  // epilogue bias + per-thread k-slice constants (global, L2-hot; no LDS dep)
  float b2v[8];
#pragma unroll
  for (int u = 0; u < 8; ++u)
    b2v[u] = b2[half * 512 + wv * 128 + u * 16 + (lane & 15)];
  const int i = t & 15;
  const int k0 = ((t >> 6) & 1) * 32 + ((t >> 4) & 3) * 8;
  float w0[8], w1[8];
#pragma unroll
  for (int e = 0; e < 8; ++e) {
    w0[e] = wc[k0 + e];
    w1[e] = wc[64 + k0 + e];
  }
  __syncthreads();

  // Phase 1: A build. Granule G = t + 256c -> j = (t>>7)+2c.
  {
    float exi = exy[i], eyi = exy[16 + i];
#pragma unroll
    for (int c = 0; c < 8; ++c) {
      int j = (t >> 7) + 2 * c;
      float rx = exy[j] - exi;
      float ry = exy[16 + j] - eyi;
      const f32x4* hp2 = (const f32x4*)&hWs[j][k0];
      f32x4 h0 = hp2[0], h1 = hp2[1];
      float hv[8] = {h0[0], h0[1], h0[2], h0[3], h1[0], h1[1], h1[2], h1[3]};
      bf16x8 pk;
#pragma unroll
      for (int e = 0; e < 8; ++e) {
        float v = fmaf(rx, w0[e], fmaf(ry, w1[e], hv[e]));
        v = fmaxf(v, 0.f);
        pk[e] = (short)f2bf(v);
      }
      Afrag[t + 256 * c] = pk;
    }
  }

  // Pass-0 B-fragments issued BEFORE the barrier (global loads, no LDS dep):
  // their ~500cyc latency overlaps the barrier + other waves' A-build tail.
  bf16x8 bfr[4][2];
#pragma unroll
  for (int u = 0; u < 4; ++u) {
    int nt = half * 32 + wv * 8 + u;
    bfr[u][0] = *(const bf16x8*)(w2f + ((nt * 2 + 0) * 64 + lane) * 8);
    bfr[u][1] = *(const bf16x8*)(w2f + ((nt * 2 + 1) * 64 + lane) * 8);
  }
  __syncthreads();

  // Phase 2: GEMM + register pooling, 2 passes of 4 ntiles.
  const int rowbase = (g * 16 + (lane >> 4) * 4) * 1024 + half * 512 + wv * 128 + (lane & 15);
  const bf16x8* ap = Afrag + lane;
  const f32x4 NEGINF = {-3.4e38f, -3.4e38f, -3.4e38f, -3.4e38f};
#pragma unroll
  for (int pass = 0; pass < 2; ++pass) {
    if (pass == 1) {
      // load pass-1 B-fragments (overlaps with pass-0 epilogue below)
#pragma unroll
      for (int u = 0; u < 4; ++u) {
        int nt = half * 32 + wv * 8 + 4 + u;
        bfr[u][0] = *(const bf16x8*)(w2f + ((nt * 2 + 0) * 64 + lane) * 8);
        bfr[u][1] = *(const bf16x8*)(w2f + ((nt * 2 + 1) * 64 + lane) * 8);
      }
    }
    f32x4 pool[4];
#pragma unroll
    for (int u = 0; u < 4; ++u) pool[u] = NEGINF;

    bf16x8 a0 = ap[0];
    bf16x8 a1 = ap[64];
#pragma unroll 4
    for (int j = 0; j < 16; ++j) {
      f32x4 acc0[4], acc1[4];
      __builtin_amdgcn_s_setprio(1);
#pragma unroll
      for (int u = 0; u < 4; ++u) {
        f32x4 z = {0.f, 0.f, 0.f, 0.f};
        acc0[u] = __builtin_amdgcn_mfma_f32_16x16x32_bf16(a0, bfr[u][0], z, 0, 0, 0);
      }
#pragma unroll
      for (int u = 0; u < 4; ++u) {
        f32x4 z = {0.f, 0.f, 0.f, 0.f};
        acc1[u] = __builtin_amdgcn_mfma_f32_16x16x32_bf16(a1, bfr[u][1], z, 0, 0, 0);
      }
      __builtin_amdgcn_s_setprio(0);
      int jn = (j + 1) & 15;  // wrap harmless
      a0 = ap[jn * 128];
      a1 = ap[jn * 128 + 64];
#pragma unroll
      for (int u = 0; u < 4; ++u)
#pragma unroll
        for (int r = 0; r < 4; ++r)
          pool[u][r] = fmaxf(pool[u][r], acc0[u][r] + acc1[u][r]);
    }

#pragma unroll
    for (int u = 0; u < 4; ++u) {
      float bb = b2v[pass * 4 + u];
#pragma unroll
      for (int r = 0; r < 4; ++r)
        out[rowbase + r * 1024 + (pass * 4 + u) * 16] = fmaxf(pool[u][r] + bb, 0.f);
    }
  }
}

extern "C" void kernel_launch(void* const* d_in, const int* in_sizes, int n_in,
                              void* d_out, int out_size, void* d_ws, size_t ws_size,
                              hipStream_t stream) {
  const float* in_xy = (const float*)d_in[0];
  const float* h_states = (const float*)d_in[2];
  const float* W_emb = (const float*)d_in[4];
  const float* b_emb = (const float*)d_in[5];
  const float* W1 = (const float*)d_in[6];
  const float* b1 = (const float*)d_in[7];
  const float* W2 = (const float*)d_in[8];
  const float* b2 = (const float*)d_in[9];
  float* out = (float*)d_out;

  unsigned short* w2f = (unsigned short*)d_ws;                     // 128 KB @ 0
  float* wc = (float*)((char*)d_ws + 131072);                      // 768 B
  unsigned short* w1bf = (unsigned short*)((char*)d_ws + 132096);  // 8 KB

  prep_kernel<<<35, 256, 0, stream>>>(W2, W_emb, b_emb, W1, w2f, wc, w1bf);
  pool_kernel<<<1024, 256, 0, stream>>>(in_xy, h_states, b1, b2, w2f, wc, w1bf, out);
}

// Round 12
// 26.436 us; speedup vs baseline: 1.3752x; 1.1303x over previous
//
#include <hip/hip_runtime.h>
#include <hip/hip_bf16.h>

typedef __attribute__((ext_vector_type(8))) short bf16x8;
typedef __attribute__((ext_vector_type(4))) float f32x4;

#define NB 8192
#define NS 8

__device__ __forceinline__ unsigned short f2bf(float f) {
  union { float f; unsigned int u; } v; v.f = f;
  unsigned int r = v.u + 0x7FFFu + ((v.u >> 16) & 1u);
  return (unsigned short)(r >> 16);
}

// prep: W2 -> bf16 B-fragments (w2f); Wc = [W_emb;b_emb]@W1a (wc);
//       W1b (rows 64..127) -> bf16 B-fragments (w1bf)
__global__ __launch_bounds__(256) void prep_kernel(
    const float* __restrict__ W2, const float* __restrict__ W_emb,
    const float* __restrict__ b_emb, const float* __restrict__ W1,
    unsigned short* __restrict__ w2f, float* __restrict__ wc,
    unsigned short* __restrict__ w1bf) {
  int tid = blockIdx.x * 256 + threadIdx.x;
  if (tid < 8192) {
    int lane = tid & 63;
    int ks = (tid >> 6) & 1;
    int nt = tid >> 7;
    int col = nt * 16 + (lane & 15);
    int k0 = ks * 32 + (lane >> 4) * 8;
    bf16x8 pk;
#pragma unroll
    for (int e = 0; e < 8; ++e)
      pk[e] = (short)f2bf(W2[(k0 + e) * 1024 + col]);
    *(bf16x8*)(w2f + tid * 8) = pk;
  } else if (tid < 8192 + 192) {
    int t2 = tid - 8192;
    int c = t2 >> 6, k = t2 & 63;
    float s = 0.f;
    for (int e = 0; e < 64; ++e) {
      float src = (c < 2) ? W_emb[c * 64 + e] : b_emb[e];
      s += src * W1[e * 64 + k];
    }
    wc[t2] = s;  // wc0[k], wc1[k], cbe[k]
  } else if (tid < 8192 + 192 + 512) {
    int q = tid - 8384;
    int lane = q & 63;
    int fr = q >> 6;          // nt*2 + ks
    int nt = fr >> 1, ks = fr & 1;
    int col = nt * 16 + (lane & 15);
    int e0 = ks * 32 + (lane >> 4) * 8;
    bf16x8 pk;
#pragma unroll
    for (int e = 0; e < 8; ++e)
      pk[e] = (short)f2bf(W1[(64 + e0 + e) * 64 + col]);
    *(bf16x8*)(w1bf + q * 8) = pk;
  }
}

// pool: block = one group, 512 threads (8 waves), launch_bounds(512,4) ->
// 2 blocks/CU, 16 waves/CU (same occupancy as before but HALF the prologue
// work per CU: one A-build/hW/exy per group instead of two).
// Phase 0: hW tile via MFMA (waves 0-3); Phase 1: A (tile=j) into LDS in
// fragment order, one granule-quad per thread; pass-0 B-frags issued before
// the barrier. Phase 2: identical to the best (R7) register-pool j-loop.
__global__ __launch_bounds__(512, 4) void pool_kernel(
    const float* __restrict__ in_xy, const float* __restrict__ h_states,
    const float* __restrict__ b1, const float* __restrict__ b2,
    const unsigned short* __restrict__ w2f, const float* __restrict__ wc,
    const unsigned short* __restrict__ w1bf, float* __restrict__ out) {
  __shared__ bf16x8 Afrag[2048];  // 32 KB, fragment-ordered A (256x64 bf16), tile=j
  __shared__ float hWs[16][72];   // hW tile (pad 72 -> 16B-aligned rows)
  __shared__ float exy[32];       // x[0:16], y[16:32]
  const int g = blockIdx.x;
  const int t = threadIdx.x;
  const int lane = t & 63;
  const int wv = t >> 6;  // 0..7

  if (t < 32) {
    int p = t & 15;
    exy[t] = in_xy[((NS - 1) * NB + g * 16 + p) * 2 + (t >> 4)];
  }

  // Phase 0: hW[j][k] = b1[k] + cbe[k] + h[g*16+j] @ W1b. Waves 0-3 -> ntile wv.
  if (wv < 4) {
    const int row = g * 16 + (lane & 15);
    const int e0 = (lane >> 4) * 8;
    const float* hp = h_states + row * 64 + e0;
    bf16x8 ha0, ha1;
#pragma unroll
    for (int e = 0; e < 8; ++e) {
      ha0[e] = (short)f2bf(hp[e]);
      ha1[e] = (short)f2bf(hp[e + 32]);
    }
    bf16x8 bf0 = *(const bf16x8*)(w1bf + ((wv * 2 + 0) * 64 + lane) * 8);
    bf16x8 bf1 = *(const bf16x8*)(w1bf + ((wv * 2 + 1) * 64 + lane) * 8);
    f32x4 z = {0.f, 0.f, 0.f, 0.f};
    f32x4 acc = __builtin_amdgcn_mfma_f32_16x16x32_bf16(ha0, bf0, z, 0, 0, 0);
    acc = __builtin_amdgcn_mfma_f32_16x16x32_bf16(ha1, bf1, acc, 0, 0, 0);
    int col = wv * 16 + (lane & 15);
    float bb = b1[col] + wc[128 + col];
#pragma unroll
    for (int r = 0; r < 4; ++r)
      hWs[(lane >> 4) * 4 + r][col] = acc[r] + bb;
  }

  // epilogue bias + per-thread k-slice constants (global, L2-hot; no LDS dep)
  float b2v[8];
#pragma unroll
  for (int u = 0; u < 8; ++u)
    b2v[u] = b2[wv * 128 + u * 16 + (lane & 15)];
  const int i = t & 15;
  const int k0 = ((t >> 6) & 1) * 32 + ((t >> 4) & 3) * 8;
  float w0[8], w1[8];
#pragma unroll
  for (int e = 0; e < 8; ++e) {
    w0[e] = wc[k0 + e];
    w1[e] = wc[64 + k0 + e];
  }
  __syncthreads();

  // Phase 1: A build. Granule G = t + 512c -> lane=G&63, ks=(G>>6)&1,
  // j = (t>>7) + 4c. A_j[i,k] = relu(rel(i,j)x*wc0 + rel(i,j)y*wc1 + hW[j][k])
  {
    float exi = exy[i], eyi = exy[16 + i];
#pragma unroll
    for (int c = 0; c < 4; ++c) {
      int j = (t >> 7) + 4 * c;
      float rx = exy[j] - exi;
      float ry = exy[16 + j] - eyi;
      const f32x4* hp2 = (const f32x4*)&hWs[j][k0];
      f32x4 h0 = hp2[0], h1 = hp2[1];
      float hv[8] = {h0[0], h0[1], h0[2], h0[3], h1[0], h1[1], h1[2], h1[3]};
      bf16x8 pk;
#pragma unroll
      for (int e = 0; e < 8; ++e) {
        float v = fmaf(rx, w0[e], fmaf(ry, w1[e], hv[e]));
        v = fmaxf(v, 0.f);
        pk[e] = (short)f2bf(v);
      }
      Afrag[t + 512 * c] = pk;
    }
  }

  // Pass-0 B-fragments issued BEFORE the barrier: global-load latency overlaps
  // the barrier + other waves' A-build tail.
  bf16x8 bfr[4][2];
#pragma unroll
  for (int u = 0; u < 4; ++u) {
    int nt = wv * 8 + u;
    bfr[u][0] = *(const bf16x8*)(w2f + ((nt * 2 + 0) * 64 + lane) * 8);
    bfr[u][1] = *(const bf16x8*)(w2f + ((nt * 2 + 1) * 64 + lane) * 8);
  }
  __syncthreads();

  // Phase 2: GEMM + register pooling, 2 passes of 4 ntiles, acc double-buffer.
  const int rowbase = (g * 16 + (lane >> 4) * 4) * 1024 + wv * 128 + (lane & 15);
  const bf16x8* ap = Afrag + lane;
  const f32x4 NEGINF = {-3.4e38f, -3.4e38f, -3.4e38f, -3.4e38f};
#pragma unroll
  for (int pass = 0; pass < 2; ++pass) {
    if (pass == 1) {
#pragma unroll
      for (int u = 0; u < 4; ++u) {
        int nt = wv * 8 + 4 + u;
        bfr[u][0] = *(const bf16x8*)(w2f + ((nt * 2 + 0) * 64 + lane) * 8);
        bfr[u][1] = *(const bf16x8*)(w2f + ((nt * 2 + 1) * 64 + lane) * 8);
      }
    }
    f32x4 pool[4], accB[4];
#pragma unroll
    for (int u = 0; u < 4; ++u) { pool[u] = NEGINF; accB[u] = NEGINF; }

    bf16x8 a0 = ap[0];
    bf16x8 a1 = ap[64];
#pragma unroll
    for (int jj = 0; jj < 16; jj += 2) {
      // even iter -> accA; pool-fmax consumes accB (iter jj-1; -inf at jj=0)
      f32x4 accA[4];
      __builtin_amdgcn_s_setprio(1);
#pragma unroll
      for (int u = 0; u < 4; ++u) {
        f32x4 z = {0.f, 0.f, 0.f, 0.f};
        accA[u] = __builtin_amdgcn_mfma_f32_16x16x32_bf16(a0, bfr[u][0], z, 0, 0, 0);
      }
#pragma unroll
      for (int u = 0; u < 4; ++u)
        accA[u] = __builtin_amdgcn_mfma_f32_16x16x32_bf16(a1, bfr[u][1], accA[u], 0, 0, 0);
      __builtin_amdgcn_s_setprio(0);
      bf16x8 c0 = ap[(jj + 1) * 128];
      bf16x8 c1 = ap[(jj + 1) * 128 + 64];
#pragma unroll
      for (int u = 0; u < 4; ++u)
#pragma unroll
        for (int r = 0; r < 4; ++r) pool[u][r] = fmaxf(pool[u][r], accB[u][r]);

      // odd iter -> accB; pool-fmax consumes accA
      __builtin_amdgcn_s_setprio(1);
#pragma unroll
      for (int u = 0; u < 4; ++u) {
        f32x4 z = {0.f, 0.f, 0.f, 0.f};
        accB[u] = __builtin_amdgcn_mfma_f32_16x16x32_bf16(c0, bfr[u][0], z, 0, 0, 0);
      }
#pragma unroll
      for (int u = 0; u < 4; ++u)
        accB[u] = __builtin_amdgcn_mfma_f32_16x16x32_bf16(c1, bfr[u][1], accB[u], 0, 0, 0);
      __builtin_amdgcn_s_setprio(0);
      int jn = (jj + 2) & 15;  // wrap harmless
      a0 = ap[jn * 128];
      a1 = ap[jn * 128 + 64];
#pragma unroll
      for (int u = 0; u < 4; ++u)
#pragma unroll
        for (int r = 0; r < 4; ++r) pool[u][r] = fmaxf(pool[u][r], accA[u][r]);
    }
    // tail: accB holds j=15
#pragma unroll
    for (int u = 0; u < 4; ++u)
#pragma unroll
      for (int r = 0; r < 4; ++r) pool[u][r] = fmaxf(pool[u][r], accB[u][r]);

#pragma unroll
    for (int u = 0; u < 4; ++u) {
      float bb = b2v[pass * 4 + u];
#pragma unroll
      for (int r = 0; r < 4; ++r)
        out[rowbase + r * 1024 + (pass * 4 + u) * 16] = fmaxf(pool[u][r] + bb, 0.f);
    }
  }
}

extern "C" void kernel_launch(void* const* d_in, const int* in_sizes, int n_in,
                              void* d_out, int out_size, void* d_ws, size_t ws_size,
                              hipStream_t stream) {
  const float* in_xy = (const float*)d_in[0];
  const float* h_states = (const float*)d_in[2];
  const float* W_emb = (const float*)d_in[4];
  const float* b_emb = (const float*)d_in[5];
  const float* W1 = (const float*)d_in[6];
  const float* b1 = (const float*)d_in[7];
  const float* W2 = (const float*)d_in[8];
  const float* b2 = (const float*)d_in[9];
  float* out = (float*)d_out;

  unsigned short* w2f = (unsigned short*)d_ws;                     // 128 KB @ 0
  float* wc = (float*)((char*)d_ws + 131072);                      // 768 B
  unsigned short* w1bf = (unsigned short*)((char*)d_ws + 132096);  // 8 KB

  prep_kernel<<<35, 256, 0, stream>>>(W2, W_emb, b_emb, W1, w2f, wc, w1bf);
  pool_kernel<<<512, 512, 0, stream>>>(in_xy, h_states, b1, b2, w2f, wc, w1bf, out);
}